// Round 4
// baseline (1587.601 us; speedup 1.0000x reference)
//
#include <hip/hip_runtime.h>
#include <hip/hip_bf16.h>

// GroupedExperts: out[t] = (silu(x@w1[e]^T) * (x@w3[e]^T)) @ w2[e]^T
// E=8, T=16384, D=2048, H=5632; tokens pre-sorted by expert, even split.
//
// Round 4: 32x32x16 MFMA, 256x256 tile BK=64, 8 waves, 2-buf LDS,
// balanced 4-window schedule {4,8,4,8} ds_reads, uniform counted vmcnt(4)
// with 3-window prefetch cover and barrier-separated retire->read,
// register role-swap (aX/aY) per tile parity. w2 f32->bf16 convert fused
// into k_gate_up blocks (if ws_size permits a disjoint w2b region).

typedef __bf16 bf16x8 __attribute__((ext_vector_type(8)));
typedef float f32x16 __attribute__((ext_vector_type(16)));
typedef unsigned short u16x8 __attribute__((ext_vector_type(8)));

constexpr int E = 8;
constexpr int T = 16384;
constexpr int D = 2048;
constexpr int H = 5632;

#define DEV static __device__ __forceinline__

DEV unsigned short f2bf(float f) {
    unsigned u = __builtin_bit_cast(unsigned, f);
    u = (u + 0x7FFFu + ((u >> 16) & 1u)) >> 16;   // RNE
    return (unsigned short)u;
}

DEV void gload16(const void* g, void* l) {
    __builtin_amdgcn_global_load_lds(
        (const __attribute__((address_space(1))) void*)g,
        (__attribute__((address_space(3))) void*)l, 16, 0, 0);
}

DEV f32x16 mfma32(bf16x8 a, bf16x8 b, f32x16 c) {
    return __builtin_amdgcn_mfma_f32_32x32x16_bf16(a, b, c, 0, 0, 0);
}

DEV void vm4() { asm volatile("s_waitcnt vmcnt(4)" ::: "memory"); }
DEV void vm2() { asm volatile("s_waitcnt vmcnt(2)" ::: "memory"); }
DEV void vm0() { asm volatile("s_waitcnt vmcnt(0)" ::: "memory"); }
DEV void barsb() {
    __builtin_amdgcn_s_barrier();
    __builtin_amdgcn_sched_barrier(0);
}

DEV void cvt8(const float* src, unsigned short* dst) {
    float4 a = *(const float4*)src;
    float4 c = *(const float4*)(src + 4);
    u16x8 r;
    r[0] = f2bf(a.x); r[1] = f2bf(a.y); r[2] = f2bf(a.z); r[3] = f2bf(a.w);
    r[4] = f2bf(c.x); r[5] = f2bf(c.y); r[6] = f2bf(c.z); r[7] = f2bf(c.w);
    *(u16x8*)dst = r;
}

// ---------------- expert lookup for a row tile ----------------------------
DEV int expert_of_row(const int* __restrict__ ntp, int row0) {
    int e = 0, s = 0;
    for (int i = 0; i < E; ++i) {
        int c = ntp[i];
        if (row0 < s + c) { e = i; break; }
        s += c;
    }
    return e;
}

// ---------------- pre-GEMM converts: x (linear) + w1/w3 (interleave-32) ---
// w13b[e] row layout: rr = (h>>5)*64 + which*32 + (h&31); which 0=w1, 1=w3.
__global__ __launch_bounds__(256) void k_cvt_pre(
    const float* __restrict__ x, const float* __restrict__ w1,
    const float* __restrict__ w3, unsigned short* __restrict__ xb,
    unsigned short* __restrict__ w13b) {
    const int bid = blockIdx.x, tid = threadIdx.x;
    if (bid < 512) {
        const long n8 = (long)T * D / 8;
        for (long i = (long)bid * 256 + tid; i < n8; i += 512L * 256)
            cvt8(x + i * 8, xb + i * 8);
    } else {
        const float* src = (bid < 1408) ? w1 : w3;
        const int which = (bid < 1408) ? 0 : 1;
        const int b0 = (bid < 1408) ? 512 : 1408;
        const long n8 = (long)E * H * D / 8;
        for (long i = (long)(bid - b0) * 256 + tid; i < n8; i += 896L * 256) {
            int col8 = (int)(i & 255);          // D/8 = 256
            int rowi = (int)(i >> 8);           // e*H + h
            int e = rowi / H;
            int h = rowi - e * H;
            int rr = ((h >> 5) << 6) + (which << 5) + (h & 31);
            cvt8(src + i * 8,
                 w13b + ((size_t)e * (2 * H) + rr) * D + (size_t)col8 * 8);
        }
    }
}

// fallback linear cvt (w2, when ws too small to overlap)
__global__ __launch_bounds__(256) void k_cvt(const float* __restrict__ in,
                                             unsigned short* __restrict__ out,
                                             long n8) {
    long i = (long)blockIdx.x * blockDim.x + threadIdx.x;
    long stride = (long)gridDim.x * blockDim.x;
    for (; i < n8; i += stride) cvt8(in + i * 8, out + i * 8);
}

// ---------------- 256x256 BK=64 gemm core (32x32x16 MFMA) -----------------
// 512 thr = 8 waves (2M x 4N); wave out 128x64 = acc[4][2] f32x16.
// LDS: sA,sB = 2 buf x 256 rows x 64 el (128B rows) = 64 KiB each.
// Swizzle: 16B slot s of row r stored at s^(r&7); inverse-swizzled global
// source, linear global_load_lds dest.
// Windows per tile: P0{vm4; rd bLo(4); st B1(kt+1); bar; mfma m01xn0}
//                   P1{vm4; rd aHi(8); st A2(kt+1); bar; mfma m23xn0}
//                   P2{vm4; rd bHi(4); st B2(kt+1); bar; mfma m23xn1}
//                   P3{vm4; rd aLo(kt+1)(8); st A1(kt+2); bar; mfma m01xn1}
// Every read is preceded (>=1 window earlier) by the vmcnt retiring its
// stage unit AND a barrier -> cross-wave safe. 6 loads in flight steady.
template <int LD, int NT>
DEV void gemm32(const unsigned short* pa, const unsigned short* pb,
                unsigned short* sA, unsigned short* sB, int tid,
                f32x16 (&acc)[4][2]) {
    const int lane = tid & 63, wid = tid >> 6;
    const int wm = wid >> 2, wn = wid & 3;
    const int hi5 = lane >> 5, l7 = lane & 7;
    int slot[4];
#pragma unroll
    for (int kk = 0; kk < 4; ++kk) slot[kk] = ((kk * 2 + hi5) ^ l7) << 3;
    const int arow = (wm * 128 + (lane & 31)) * 64;
    const int brow = (wn * 64 + (lane & 31)) * 64;
    char* ldsA = (char*)sA;
    char* ldsB = (char*)sB;
    const int dA = wid << 10;
    const int dB = ((wid >> 2) << 13) + ((wid & 3) << 10);

    bf16x8 aX[2][4], aY[2][4], b[4];

    auto stA = [&](const unsigned short* g, int off) {
        gload16(g, ldsA + off + dA);
        gload16(g + (size_t)128 * LD, ldsA + off + dA + 16384);
    };
    auto stB = [&](const unsigned short* g, int off) {
        gload16(g, ldsB + off + dB);
        gload16(g + (size_t)128 * LD, ldsB + off + dB + 16384);
    };
    auto rdA = [&](bf16x8 (&dst)[2][4], int off) {
#pragma unroll
        for (int m = 0; m < 2; ++m)
#pragma unroll
            for (int kk = 0; kk < 4; ++kk)
                dst[m][kk] =
                    *(const bf16x8*)&sA[off + arow + m * 2048 + slot[kk]];
    };
    auto rdB = [&](int off, int half) {
#pragma unroll
        for (int kk = 0; kk < 4; ++kk)
            b[kk] = *(const bf16x8*)&sB[off + brow + half * 2048 + slot[kk]];
    };
    auto mm = [&](bf16x8 (&A)[2][4], int mb, int n) {
#pragma unroll
        for (int m = 0; m < 2; ++m)
#pragma unroll
            for (int kk = 0; kk < 4; ++kk)
                acc[mb + m][n] = mfma32(A[m][kk], b[kk], acc[mb + m][n]);
    };

    // prologue: tile0 -> buf0; read aLo(0); A1(1) -> buf1
    stA(pa, 0);                 // A1(0): rows {0-63,128-191}
    stB(pb, 0);                 // B1(0): rows {0-31,64-95,...} (n=0 set)
    stA(pa + 64 * LD, 8192);    // A2(0)
    stB(pb + 32 * LD, 4096);    // B2(0)
    vm4();                      // retire A1(0), B1(0)
    __builtin_amdgcn_s_barrier();
    rdA(aX, 0);                 // aLo(0)
    stA(pa + 64, 32768);        // A1(1) -> buf1
    // outstanding: {A2(0), B2(0), A1(1)} = 6 loads  (steady-state ledger)

    auto tile = [&](int cbW, int o1, int o2, bool steady, bool st2,
                    bf16x8 (&A0)[2][4], bf16x8 (&A1)[2][4]) {
        const int cbB = cbW << 1;      // current buf byte offset
        const int nbB = cbB ^ 32768;   // next buf byte offset
        // ---- W_P0 ----
        if (steady) vm4(); else vm2();     // retire A2(kt)
        rdB(cbW, 0);                       // bLo (B1(kt): retired+bar'd)
        if (steady) stB(pb + o1, nbB);     // B1(kt+1)
        barsb();
        __builtin_amdgcn_s_setprio(1); mm(A0, 0, 0);
        __builtin_amdgcn_s_setprio(0);
        // ---- W_P1 ----
        if (steady) vm4(); else vm0();     // retire B2(kt)
        rdA(A1, cbW + 4096);               // aHi (A2(kt): retired+bar'd)
        if (steady) stA(pa + o1 + 64 * LD, nbB + 8192);  // A2(kt+1)
        barsb();
        __builtin_amdgcn_s_setprio(1); mm(A1, 2, 0);
        __builtin_amdgcn_s_setprio(0);
        // ---- W_P2 ----
        if (steady) vm4();                 // retire A1(kt+1)
        rdB(cbW, 1);                       // bHi (B2(kt): retired+bar'd)
        if (steady) stB(pb + o1 + 32 * LD, nbB + 4096);  // B2(kt+1)
        barsb();
        __builtin_amdgcn_s_setprio(1); mm(A1, 2, 1);
        __builtin_amdgcn_s_setprio(0);
        // ---- W_P3 ----
        if (steady) {
            vm4();                         // retire B1(kt+1)
            rdA(A1, cbW ^ 16384);          // aLo(kt+1) (A1(kt+1) retired+bar'd)
            if (st2) stA(pa + o2, cbB);    // A1(kt+2) -> current-parity buf
            barsb();
        }
        __builtin_amdgcn_s_setprio(1); mm(A0, 0, 1);
        __builtin_amdgcn_s_setprio(0);
    };

#pragma unroll 1
    for (int kt = 0; kt < NT - 2; kt += 2) {
        tile(0, 64, 128, true, true, aX, aY);
        tile(16384, 128, 192, true, true, aY, aX);
        pa += 128;
        pb += 128;
    }
    tile(0, 64, 128, true, false, aX, aY);    // kt = NT-2: skip A1(NT) stage
    tile(16384, 0, 0, false, false, aY, aX);  // kt = NT-1: tail vmcnts
}

// ---------------- kernel 1: fused gate/up grouped GEMM + SwiGLU -----------
// A = xb (T x D), B = w13b[e] (2H x D interleave-32), h (T x H bf16).
// Optional fused w2 f32->bf16 convert (disjoint w2b region).
__global__ __launch_bounds__(512, 2) void k_gate_up(
    const unsigned short* __restrict__ xb,
    const unsigned short* __restrict__ w13b,
    const float* __restrict__ w2, unsigned short* __restrict__ w2b,
    const int* __restrict__ ntp, unsigned short* __restrict__ hbuf) {
    __shared__ unsigned short sA[2 * 16384];
    __shared__ unsigned short sB[2 * 16384];

    const int bid = blockIdx.x;
    const int tid = threadIdx.x;

    if (w2) {  // fused w2 convert: 4096 8-el chunks per block, then drain
        const float* src = w2 + (size_t)bid * 32768;
        unsigned short* dst = w2b + (size_t)bid * 32768;
#pragma unroll
        for (int it = 0; it < 8; ++it) {
            int o = (it * 512 + tid) * 8;
            cvt8(src + o, dst + o);
        }
        vm0();  // clean vmcnt ledger before the counted-vmcnt GEMM
    }

    // block -> (expert-group, tn, tm) : eg pinned per XCD, tm-within-expert
    // fastest, so an XCD's concurrent blocks share one expert's B-panels.
    const int eg = bid & 7;
    const int tm = eg * 8 + ((bid >> 3) & 7);
    const int tn = bid >> 6;  // [0,44)

    const int row0 = tm << 8;
    const int e = expert_of_row(ntp, row0);
    const int lane = tid & 63, wid = tid >> 6;

    // staging sources (inverse-swizzled 16B slot)
    const int sra = tid >> 3;
    const int sca = (tid & 7) ^ (sra & 7);
    const unsigned short* pa = xb + (size_t)(row0 + sra) * D + sca * 8;
    const int brw = ((wid >> 2) << 6) + ((wid & 3) << 3) + (lane >> 3);
    const int scb = (lane & 7) ^ (lane >> 3);
    const unsigned short* pb =
        w13b + ((size_t)e * (2 * H) + (tn << 8) + brw) * D + scb * 8;

    f32x16 acc[4][2] = {};
    gemm32<D, D / 64>(pa, pb, sA, sB, tid, acc);

    // Epilogue: n=0 gate, n=1 up (interleave-32). C/D (32x32):
    // col = lane&31, row = (r&3) + 8*(r>>2) + 4*(lane>>5).
    const int wm = wid >> 2, wn = wid & 3;
    const int hc = ((tn << 2) + wn) * 32 + (lane & 31);
    const int rb = row0 + wm * 128 + ((lane >> 5) << 2);
#pragma unroll
    for (int m = 0; m < 4; ++m)
#pragma unroll
        for (int r = 0; r < 16; ++r) {
            float g = acc[m][0][r], u = acc[m][1][r];
            float hv = g * u / (1.f + __expf(-g));
            int row = rb + m * 32 + (r & 3) + ((r >> 2) << 3);
            hbuf[(size_t)row * H + hc] = f2bf(hv);
        }
}

// ---------------- kernel 2: down grouped GEMM -----------------------------
// A = h (T x H), B = w2b[e] (D x H), out (T x D f32). K = H = 5632.
__global__ __launch_bounds__(512, 2) void k_down(
    const unsigned short* __restrict__ hbuf,
    const unsigned short* __restrict__ w2b, const int* __restrict__ ntp,
    float* __restrict__ out) {
    __shared__ unsigned short sA[2 * 16384];
    __shared__ unsigned short sB[2 * 16384];

    const int bid = blockIdx.x;
    const int tid = threadIdx.x;
    // tn pinned per XCD: each XCD keeps its 2.9MB w2 panel L2-resident.
    const int tn = bid & 7;
    const int tm = bid >> 3;

    const int row0 = tm << 8;
    const int e = expert_of_row(ntp, row0);
    const int lane = tid & 63, wid = tid >> 6;

    const int sra = tid >> 3;
    const int sca = (tid & 7) ^ (sra & 7);
    const unsigned short* pa = hbuf + (size_t)(row0 + sra) * H + sca * 8;
    const int brw = ((wid >> 2) << 6) + ((wid & 3) << 3) + (lane >> 3);
    const int scb = (lane & 7) ^ (lane >> 3);
    const unsigned short* pb =
        w2b + ((size_t)e * D + (tn << 8) + brw) * H + scb * 8;

    f32x16 acc[4][2] = {};
    gemm32<H, H / 64>(pa, pb, sA, sB, tid, acc);

    const int wm = wid >> 2, wn = wid & 3;
    const int dc = (tn << 8) + (wn << 6) + (lane & 31);
    const int rb = row0 + wm * 128 + ((lane >> 5) << 2);
#pragma unroll
    for (int m = 0; m < 4; ++m)
#pragma unroll
        for (int n = 0; n < 2; ++n)
#pragma unroll
            for (int r = 0; r < 16; ++r) {
                int row = rb + m * 32 + (r & 3) + ((r >> 2) << 3);
                out[(size_t)row * D + dc + n * 32] = acc[m][n][r];
            }
}

extern "C" void kernel_launch(void* const* d_in, const int* in_sizes, int n_in,
                              void* d_out, int out_size, void* d_ws,
                              size_t ws_size, hipStream_t stream) {
    const float* x = (const float*)d_in[0];
    const float* w1 = (const float*)d_in[1];
    const float* w2 = (const float*)d_in[2];
    const float* w3 = (const float*)d_in[3];
    const int* ntp = (const int*)d_in[4];
    float* out = (float*)d_out;

    char* ws = (char*)d_ws;
    // ws layout (bytes):
    //   xb  : [0, 67108864)                       T*D*2
    //   w13b: [67108864, 436207616)               E*2H*D*2
    //   h   : [436207616, 620756992)              T*H*2
    //   w2b : [620756992, 805306368)  if ws fits  E*D*H*2 (else alias w13b)
    unsigned short* xb = (unsigned short*)(ws + 0);
    unsigned short* w13b = (unsigned short*)(ws + 67108864L);
    unsigned short* hbuf = (unsigned short*)(ws + 436207616L);
    const bool big = ws_size >= 805306368UL;
    unsigned short* w2b =
        big ? (unsigned short*)(ws + 620756992L) : w13b;

    k_cvt_pre<<<2304, 256, 0, stream>>>(x, w1, w3, xb, w13b);

    k_gate_up<<<(T / 256) * (2 * H / 256), 512, 0, stream>>>(
        xb, w13b, big ? w2 : nullptr, big ? w2b : nullptr, ntp, hbuf);

    if (!big)
        k_cvt<<<2048, 256, 0, stream>>>(w2, w2b, (long)E * D * H / 8);

    k_down<<<(T / 256) * (D / 256), 512, 0, stream>>>(hbuf, w2b, ntp, out);
}